// Round 1
// 622.521 us; speedup vs baseline: 1.5867x; 1.5867x over previous
//
#include <hip/hip_runtime.h>

// SuppAlignLayer: 4-level ROI Align, B=2, C=256, N=512 boxes/batch, OUT=7, SR=2.
// Output per level: (1024, 256, 7, 7) fp32, levels concatenated flat.
//
// v2 (this round):
//  - x-pair merge: each bilinear sample reads TWO float2 (rows y0 and y1) instead
//    of four scalar floats. Gather lane-request count halves (the saturated
//    resource per rocprof: VALUBusy 15%, HBM 20%, occupancy 73% -> request-bound).
//    Right-edge case (x0 == W-1) folds to px = W-2 with weights (0, hy)/(0, ly):
//    exactly equivalent math.
//  - Conflict-free LDS: SoA metadata arrays indexed s = sub*49 + bin, so the 64
//    lanes (consecutive bins) read consecutive dwords. Old int4[bin*4+sub] layout
//    put all lanes on 2 of 32 banks (SQ_LDS_BANK_CONFLICT = 8.3e7 ~ 17% of time).
//  - 2-item interleave in the channel loop for 2x loads-in-flight (latency-bound,
//    VGPR headroom: 36 used).

#define OUTSZ 7
#define NBIN  49
#define NSAMP 196        // 49 bins * 4 subsamples
#define ROI_STRIDE 12544u
#define LVL_STRIDE 12845056u   // 1024 * 12544

typedef float f2v __attribute__((ext_vector_type(2)));

// 8-byte load with only 4-byte alignment guarantee (gfx950 handles unaligned
// global dwordx2; worst case the backend splits it -> no worse than 2 scalars).
__device__ __forceinline__ f2v load_f2(const float* p) {
    f2v v;
    __builtin_memcpy(&v, p, 8);
    return v;
}

__global__ __launch_bounds__(256)
void roi_align_all_levels(const float* __restrict__ f0,
                          const float* __restrict__ f1,
                          const float* __restrict__ f2,
                          const float* __restrict__ f3,
                          const float* __restrict__ boxes,
                          float* __restrict__ out)
{
    // SoA sample metadata, index s = sub*49 + bin  (conflict-free ds_read_b32:
    // consecutive lanes have consecutive bins -> consecutive dwords).
    __shared__ int   sD0[NSAMP];   // y0*W + px   (top row pair base)
    __shared__ int   sD1[NSAMP];   // y1*W + px   (bottom row pair base)
    __shared__ float sW0[NSAMP];   // weight for (y0, px)
    __shared__ float sW1[NSAMP];   // weight for (y0, px+1)
    __shared__ float sW2[NSAMP];   // weight for (y1, px)
    __shared__ float sW3[NSAMP];   // weight for (y1, px+1)

    const int r   = blockIdx.x;      // roi index 0..1023
    const int lvl = blockIdx.y;      // level 0..3
    const int t   = threadIdx.x;

    int H, W; float scale; const float* feat;
    switch (lvl) {
      case 0:  H = 200; W = 304; scale = 0.25f;    feat = f0; break;
      case 1:  H = 100; W = 152; scale = 0.125f;   feat = f1; break;
      case 2:  H = 50;  W = 76;  scale = 0.0625f;  feat = f2; break;
      default: H = 25;  W = 38;  scale = 0.03125f; feat = f3; break;
    }
    const unsigned HW = (unsigned)(H * W);
    const int b = r >> 9;            // batch = roi / 512

    if (t < NSAMP) {
        const float bx1 = boxes[r * 4 + 0] * scale;
        const float by1 = boxes[r * 4 + 1] * scale;
        const float bx2 = boxes[r * 4 + 2] * scale;
        const float by2 = boxes[r * 4 + 3] * scale;
        const float rw  = fmaxf(bx2 - bx1, 1.0f);
        const float rh  = fmaxf(by2 - by1, 1.0f);

        // compute layout: t = bin*4 + sub, sub = iy*2 + ix
        const int bin = t >> 2, sub = t & 3;
        const int ph = bin / 7, pw = bin % 7;
        const int ky = 2 * ph + (sub >> 1);
        const int kx = 2 * pw + (sub & 1);

        const float gy = ((float)ky + 0.5f) * 0.5f;   // (k+0.5)/SR
        const float gx = ((float)kx + 0.5f) * 0.5f;
        const float ys = by1 + (rh / 7.0f) * gy;
        const float xs = bx1 + (rw / 7.0f) * gx;

        const float Hf = (float)H, Wf = (float)W;
        const bool vy = (ys >= -1.0f) && (ys <= Hf);
        const bool vx = (xs >= -1.0f) && (xs <= Wf);

        const float yc = fminf(fmaxf(ys, 0.0f), Hf - 1.0f);
        const float xc = fminf(fmaxf(xs, 0.0f), Wf - 1.0f);
        const int y0 = (int)yc;            // yc >= 0 -> trunc == floor
        const int x0 = (int)xc;
        const int y1i = min(y0 + 1, H - 1);
        const float ly = yc - (float)y0, lx = xc - (float)x0;
        const float hy = 1.0f - ly, hx = 1.0f - lx;

        // x-pair fold: pair covers [px, px+1], always in-bounds.
        // x0 == W-1 implies xc == W-1 (clamped), lx = 0 -> all x-weight on px+1.
        int px; float wxA, wxB;
        if (x0 < W - 1) { px = x0;     wxA = hx;   wxB = lx;   }
        else            { px = W - 2;  wxA = 0.0f; wxB = 1.0f; }

        const float vm = (vy && vx) ? 0.25f : 0.0f;   // fold mean over 2x2

        const int s = sub * NBIN + bin;               // SoA storage index
        sD0[s] = y0  * W + px;
        sD1[s] = y1i * W + px;
        sW0[s] = hy * wxA * vm;
        sW1[s] = hy * wxB * vm;
        sW2[s] = ly * wxA * vm;
        sW3[s] = ly * wxB * vm;
    }
    __syncthreads();

    const float* base = feat + (size_t)b * (size_t)(256u * HW);
    float* o = out + (size_t)lvl * LVL_STRIDE + (size_t)r * ROI_STRIDE;

    // Item loop (item = c*49 + bin): coalesced stores. Two items per iteration
    // for doubled memory-level parallelism.
    #pragma unroll 1
    for (int i = 0; i < 48; i += 2) {
        const int itemA = i * 256 + t;
        const int itemB = itemA + 256;
        const unsigned cA = (unsigned)itemA / 49u;    // magic-mul div
        const unsigned cB = (unsigned)itemB / 49u;
        const int binA = itemA - (int)cA * 49;
        const int binB = itemB - (int)cB * 49;
        const float* pA = base + (size_t)cA * HW;
        const float* pB = base + (size_t)cB * HW;

        float accA = 0.0f, accB = 0.0f;
        #pragma unroll
        for (int sub = 0; sub < 4; ++sub) {
            const int sA = sub * NBIN + binA;
            const int sB = sub * NBIN + binB;
            const f2v a0 = load_f2(pA + sD0[sA]);
            const f2v a1 = load_f2(pA + sD1[sA]);
            const f2v b0 = load_f2(pB + sD0[sB]);
            const f2v b1 = load_f2(pB + sD1[sB]);
            accA += a0.x * sW0[sA] + a0.y * sW1[sA]
                  + a1.x * sW2[sA] + a1.y * sW3[sA];
            accB += b0.x * sW0[sB] + b0.y * sW1[sB]
                  + b1.x * sW2[sB] + b1.y * sW3[sB];
        }
        o[itemA] = accA;
        o[itemB] = accB;
    }
    {   // tail item (49 is odd)
        const int item = 48 * 256 + t;
        const unsigned c = (unsigned)item / 49u;
        const int bin = item - (int)c * 49;
        const float* p = base + (size_t)c * HW;
        float acc = 0.0f;
        #pragma unroll
        for (int sub = 0; sub < 4; ++sub) {
            const int s = sub * NBIN + bin;
            const f2v a0 = load_f2(p + sD0[s]);
            const f2v a1 = load_f2(p + sD1[s]);
            acc += a0.x * sW0[s] + a0.y * sW1[s]
                 + a1.x * sW2[s] + a1.y * sW3[s];
        }
        o[item] = acc;
    }
}

extern "C" void kernel_launch(void* const* d_in, const int* in_sizes, int n_in,
                              void* d_out, int out_size, void* d_ws, size_t ws_size,
                              hipStream_t stream) {
    const float* f0    = (const float*)d_in[0];
    const float* f1    = (const float*)d_in[1];
    const float* f2    = (const float*)d_in[2];
    const float* f3    = (const float*)d_in[3];
    const float* boxes = (const float*)d_in[4];
    float* out = (float*)d_out;

    dim3 grid(1024, 4);
    roi_align_all_levels<<<grid, 256, 0, stream>>>(f0, f1, f2, f3, boxes, out);
}

// Round 2
// 533.602 us; speedup vs baseline: 1.8511x; 1.1666x over previous
//
#include <hip/hip_runtime.h>

// SuppAlignLayer: 4-level ROI Align, B=2, C=256, N=512 boxes/batch, OUT=7, SR=2.
// Output per level: (1024, 256, 7, 7) fp32, levels concatenated flat.
//
// v3 (this round): NHWC staging.
//  NCHW gathers are structurally request-bound: every bilinear corner is needed
//  for ALL 256 channels, but channels are strided by H*W -> 64-lane scatter,
//  ~64 lines/instr, 6.7x HBM over-fetch (1.1 GB vs 165 MB unique).
//  Fix: transpose feature maps to NHWC in workspace (165 MB), then each corner
//  load is 1 KB contiguous (256 ch) = ONE coalesced dwordx4 wave-instr with 100%
//  byte utilization. Weights are wave-uniform; each lane accumulates 4 channels.
//  Output transposed back to (c*49+bin) order via padded LDS (conflict-free read),
//  preserving 1 KB coalesced stores.
//  Fallback to the v2 scattered kernel if ws_size is too small.

#define OUTSZ 7
#define NBIN  49
#define NSAMP 196
#define ROI_STRIDE 12544u
#define LVL_STRIDE 12845056u   // 1024 * 12544

typedef float f2v __attribute__((ext_vector_type(2)));
typedef float f4v __attribute__((ext_vector_type(4)));

// ---------------- workspace layout (floats) ----------------
// L0: off 0,         HW=60800  (2*60800*256 = 31,129,600)
// L1: off 31129600,  HW=15200  (+7,782,400)
// L2: off 38912000,  HW=3800   (+1,945,600)
// L3: off 40857600,  HW=950    (+486,400)  total 41,344,000 fl = 165,376,000 B
#define WS_BYTES 165376000ull

// ============================================================
// Transpose NCHW (b, 256, HW) -> NHWC (b, HW, 256), one level.
// Tile: 64 positions x 256 channels through LDS (padded row 257).
__global__ __launch_bounds__(256)
void nchw_to_nhwc(const float* __restrict__ src, float* __restrict__ dst, int HW)
{
    __shared__ float tile[64 * 257];
    const int t  = threadIdx.x;
    const int p0 = blockIdx.x * 64;
    const int b  = blockIdx.y;
    const float* s = src + (size_t)b * 256u * (size_t)HW;
    float* d       = dst + (size_t)b * (size_t)HW * 256u;

    const int pl4 = (t & 15) * 4;   // local position base (x4 vectorized)
    const int ch  = t >> 4;         // 0..15
    const int p   = p0 + pl4;

    #pragma unroll 1
    for (int cc = 0; cc < 16; ++cc) {
        const int c = cc * 16 + ch;
        if (p + 3 < HW) {
            const f4v v = *reinterpret_cast<const f4v*>(s + (size_t)c * HW + p);
            tile[(pl4 + 0) * 257 + c] = v.x;
            tile[(pl4 + 1) * 257 + c] = v.y;
            tile[(pl4 + 2) * 257 + c] = v.z;
            tile[(pl4 + 3) * 257 + c] = v.w;
        } else {
            for (int j = 0; j < 4; ++j)
                if (p + j < HW) tile[(pl4 + j) * 257 + c] = s[(size_t)c * HW + p + j];
        }
    }
    __syncthreads();

    #pragma unroll 1
    for (int i = 0; i < 64; ++i) {
        const int pp = p0 + i;
        if (pp < HW) d[(size_t)pp * 256u + t] = tile[i * 257 + t];
    }
}

// ============================================================
// NHWC gather: block = (roi, level), 256 thr = 4 waves.
// Wave w handles bins w, w+4, ...; lane l owns channels 4l..4l+3.
// Per subsample: 4 coalesced float4 loads (rows y0,y1 at x=px,px+1).
__global__ __launch_bounds__(256)
void roi_gather_nhwc(const float* __restrict__ ws, const float* __restrict__ boxes,
                     float* __restrict__ out)
{
    __shared__ float obuf[NBIN * 257];   // [bin][c], row stride 257 (readout conflict-free)

    const int r   = blockIdx.x;
    const int lvl = blockIdx.y;
    const int t   = threadIdx.x;
    const int wv  = t >> 6;
    const int l   = t & 63;

    int H, W; float scale; size_t off;
    switch (lvl) {
      case 0:  H = 200; W = 304; scale = 0.25f;    off = 0u;        break;
      case 1:  H = 100; W = 152; scale = 0.125f;   off = 31129600u; break;
      case 2:  H = 50;  W = 76;  scale = 0.0625f;  off = 38912000u; break;
      default: H = 25;  W = 38;  scale = 0.03125f; off = 40857600u; break;
    }
    const int HW = H * W;
    const int b  = r >> 9;
    const float* base = ws + off + (size_t)b * (size_t)HW * 256u;

    const float bx1 = boxes[r * 4 + 0] * scale;
    const float by1 = boxes[r * 4 + 1] * scale;
    const float bx2 = boxes[r * 4 + 2] * scale;
    const float by2 = boxes[r * 4 + 3] * scale;
    const float rw  = fmaxf(bx2 - bx1, 1.0f);
    const float rh  = fmaxf(by2 - by1, 1.0f);
    const float bw7 = rw * (1.0f / 7.0f);
    const float bh7 = rh * (1.0f / 7.0f);
    const float Hf = (float)H, Wf = (float)W;

    #pragma unroll 1
    for (int bin = wv; bin < NBIN; bin += 4) {
        const int ph = bin / 7;
        const int pw = bin - ph * 7;
        f4v acc = {0.0f, 0.0f, 0.0f, 0.0f};

        #pragma unroll
        for (int sub = 0; sub < 4; ++sub) {
            const int ky = 2 * ph + (sub >> 1);
            const int kx = 2 * pw + (sub & 1);
            const float ys = by1 + bh7 * (((float)ky + 0.5f) * 0.5f);
            const float xs = bx1 + bw7 * (((float)kx + 0.5f) * 0.5f);

            const bool vy = (ys >= -1.0f) && (ys <= Hf);
            const bool vx = (xs >= -1.0f) && (xs <= Wf);

            const float yc = fminf(fmaxf(ys, 0.0f), Hf - 1.0f);
            const float xc = fminf(fmaxf(xs, 0.0f), Wf - 1.0f);
            const int y0 = (int)yc;
            const int x0 = (int)xc;
            const int y1i = min(y0 + 1, H - 1);
            const float ly = yc - (float)y0, lx = xc - (float)x0;
            const float hy = 1.0f - ly, hx = 1.0f - lx;

            int px; float wxA, wxB;
            if (x0 < W - 1) { px = x0;     wxA = hx;   wxB = lx;   }
            else            { px = W - 2;  wxA = 0.0f; wxB = 1.0f; }

            const float vm  = (vy && vx) ? 0.25f : 0.0f;
            const float w00 = hy * wxA * vm;
            const float w01 = hy * wxB * vm;
            const float w10 = ly * wxA * vm;
            const float w11 = ly * wxB * vm;

            const float* r0 = base + (size_t)(y0  * W + px) * 256u;
            const float* r1 = base + (size_t)(y1i * W + px) * 256u;

            const f4v a0 = *reinterpret_cast<const f4v*>(r0 + 4 * l);
            const f4v b0 = *reinterpret_cast<const f4v*>(r0 + 256 + 4 * l);
            const f4v a1 = *reinterpret_cast<const f4v*>(r1 + 4 * l);
            const f4v b1 = *reinterpret_cast<const f4v*>(r1 + 256 + 4 * l);

            acc += a0 * w00 + b0 * w01 + a1 * w10 + b1 * w11;
        }

        const int s = bin * 257 + 4 * l;
        obuf[s + 0] = acc.x;
        obuf[s + 1] = acc.y;
        obuf[s + 2] = acc.z;
        obuf[s + 3] = acc.w;
    }
    __syncthreads();

    float* o = out + (size_t)lvl * LVL_STRIDE + (size_t)r * ROI_STRIDE;
    #pragma unroll 1
    for (int k = 0; k < NBIN; ++k) {
        const int item = k * 256 + t;
        const unsigned c = (unsigned)item / 49u;
        const int bin = item - (int)c * 49;
        o[item] = obuf[bin * 257 + (int)c];
    }
}

// ============================================================
// v2 fallback (scattered NCHW gather) — used only if ws too small.
__device__ __forceinline__ f2v load_f2(const float* p) {
    f2v v; __builtin_memcpy(&v, p, 8); return v;
}

__global__ __launch_bounds__(256)
void roi_align_all_levels(const float* __restrict__ f0,
                          const float* __restrict__ f1,
                          const float* __restrict__ f2,
                          const float* __restrict__ f3,
                          const float* __restrict__ boxes,
                          float* __restrict__ out)
{
    __shared__ int   sD0[NSAMP];
    __shared__ int   sD1[NSAMP];
    __shared__ float sW0[NSAMP];
    __shared__ float sW1[NSAMP];
    __shared__ float sW2[NSAMP];
    __shared__ float sW3[NSAMP];

    const int r   = blockIdx.x;
    const int lvl = blockIdx.y;
    const int t   = threadIdx.x;

    int H, W; float scale; const float* feat;
    switch (lvl) {
      case 0:  H = 200; W = 304; scale = 0.25f;    feat = f0; break;
      case 1:  H = 100; W = 152; scale = 0.125f;   feat = f1; break;
      case 2:  H = 50;  W = 76;  scale = 0.0625f;  feat = f2; break;
      default: H = 25;  W = 38;  scale = 0.03125f; feat = f3; break;
    }
    const unsigned HW = (unsigned)(H * W);
    const int b = r >> 9;

    if (t < NSAMP) {
        const float bx1 = boxes[r * 4 + 0] * scale;
        const float by1 = boxes[r * 4 + 1] * scale;
        const float bx2 = boxes[r * 4 + 2] * scale;
        const float by2 = boxes[r * 4 + 3] * scale;
        const float rw  = fmaxf(bx2 - bx1, 1.0f);
        const float rh  = fmaxf(by2 - by1, 1.0f);

        const int bin = t >> 2, sub = t & 3;
        const int ph = bin / 7, pw = bin % 7;
        const int ky = 2 * ph + (sub >> 1);
        const int kx = 2 * pw + (sub & 1);

        const float gy = ((float)ky + 0.5f) * 0.5f;
        const float gx = ((float)kx + 0.5f) * 0.5f;
        const float ys = by1 + (rh / 7.0f) * gy;
        const float xs = bx1 + (rw / 7.0f) * gx;

        const float Hf = (float)H, Wf = (float)W;
        const bool vy = (ys >= -1.0f) && (ys <= Hf);
        const bool vx = (xs >= -1.0f) && (xs <= Wf);

        const float yc = fminf(fmaxf(ys, 0.0f), Hf - 1.0f);
        const float xc = fminf(fmaxf(xs, 0.0f), Wf - 1.0f);
        const int y0 = (int)yc;
        const int x0 = (int)xc;
        const int y1i = min(y0 + 1, H - 1);
        const float ly = yc - (float)y0, lx = xc - (float)x0;
        const float hy = 1.0f - ly, hx = 1.0f - lx;

        int px; float wxA, wxB;
        if (x0 < W - 1) { px = x0;     wxA = hx;   wxB = lx;   }
        else            { px = W - 2;  wxA = 0.0f; wxB = 1.0f; }

        const float vm = (vy && vx) ? 0.25f : 0.0f;

        const int s = sub * NBIN + bin;
        sD0[s] = y0  * W + px;
        sD1[s] = y1i * W + px;
        sW0[s] = hy * wxA * vm;
        sW1[s] = hy * wxB * vm;
        sW2[s] = ly * wxA * vm;
        sW3[s] = ly * wxB * vm;
    }
    __syncthreads();

    const float* base = feat + (size_t)b * (size_t)(256u * HW);
    float* o = out + (size_t)lvl * LVL_STRIDE + (size_t)r * ROI_STRIDE;

    #pragma unroll 1
    for (int i = 0; i < 48; i += 2) {
        const int itemA = i * 256 + t;
        const int itemB = itemA + 256;
        const unsigned cA = (unsigned)itemA / 49u;
        const unsigned cB = (unsigned)itemB / 49u;
        const int binA = itemA - (int)cA * 49;
        const int binB = itemB - (int)cB * 49;
        const float* pA = base + (size_t)cA * HW;
        const float* pB = base + (size_t)cB * HW;

        float accA = 0.0f, accB = 0.0f;
        #pragma unroll
        for (int sub = 0; sub < 4; ++sub) {
            const int sA = sub * NBIN + binA;
            const int sB = sub * NBIN + binB;
            const f2v a0 = load_f2(pA + sD0[sA]);
            const f2v a1 = load_f2(pA + sD1[sA]);
            const f2v b0 = load_f2(pB + sD0[sB]);
            const f2v b1 = load_f2(pB + sD1[sB]);
            accA += a0.x * sW0[sA] + a0.y * sW1[sA]
                  + a1.x * sW2[sA] + a1.y * sW3[sA];
            accB += b0.x * sW0[sB] + b0.y * sW1[sB]
                  + b1.x * sW2[sB] + b1.y * sW3[sB];
        }
        o[itemA] = accA;
        o[itemB] = accB;
    }
    {
        const int item = 48 * 256 + t;
        const unsigned c = (unsigned)item / 49u;
        const int bin = item - (int)c * 49;
        const float* p = base + (size_t)c * HW;
        float acc = 0.0f;
        #pragma unroll
        for (int sub = 0; sub < 4; ++sub) {
            const int s = sub * NBIN + bin;
            const f2v a0 = load_f2(p + sD0[s]);
            const f2v a1 = load_f2(p + sD1[s]);
            acc += a0.x * sW0[s] + a0.y * sW1[s]
                 + a1.x * sW2[s] + a1.y * sW3[s];
        }
        o[item] = acc;
    }
}

extern "C" void kernel_launch(void* const* d_in, const int* in_sizes, int n_in,
                              void* d_out, int out_size, void* d_ws, size_t ws_size,
                              hipStream_t stream) {
    const float* f0    = (const float*)d_in[0];
    const float* f1    = (const float*)d_in[1];
    const float* f2    = (const float*)d_in[2];
    const float* f3    = (const float*)d_in[3];
    const float* boxes = (const float*)d_in[4];
    float* out = (float*)d_out;

    if (d_ws != nullptr && ws_size >= WS_BYTES) {
        float* w = (float*)d_ws;
        nchw_to_nhwc<<<dim3(950, 2), 256, 0, stream>>>(f0, w + 0u,        60800);
        nchw_to_nhwc<<<dim3(238, 2), 256, 0, stream>>>(f1, w + 31129600u, 15200);
        nchw_to_nhwc<<<dim3(60,  2), 256, 0, stream>>>(f2, w + 38912000u, 3800);
        nchw_to_nhwc<<<dim3(15,  2), 256, 0, stream>>>(f3, w + 40857600u, 950);
        roi_gather_nhwc<<<dim3(1024, 4), 256, 0, stream>>>(w, boxes, out);
    } else {
        dim3 grid(1024, 4);
        roi_align_all_levels<<<grid, 256, 0, stream>>>(f0, f1, f2, f3, boxes, out);
    }
}